// Round 11
// baseline (1990.184 us; speedup 1.0000x reference)
//
#include <hip/hip_runtime.h>
#include <hip/hip_bf16.h>
#include <math.h>

#define B_SZ    64
#define SEQ     2048
#define DMODEL  128
#define DINNER  256
#define DSTATE  16
#define NLAYERS 5

typedef unsigned short u16;
typedef unsigned int   u32;
typedef __attribute__((ext_vector_type(8))) short bf16x8;
typedef __attribute__((ext_vector_type(4))) float f32x4;

static __device__ __forceinline__ float bf2f(u16 u){
  union { unsigned u; float f; } a; a.u = ((unsigned)u) << 16; return a.f;
}
static __device__ __forceinline__ u16 f2bf(float f){
  union { float f; unsigned u; } a; a.f = f;
  unsigned r = a.u + 0x7fffu + ((a.u >> 16) & 1u);
  return (u16)(r >> 16);
}
static __device__ __forceinline__ float sigm(float x){ return 1.f/(1.f+__expf(-x)); }
static __device__ __forceinline__ float siluf(float x){ return x/(1.f+__expf(-x)); }

#define MFMA16(a,b,c) __builtin_amdgcn_mfma_f32_16x16x32_bf16((a),(b),(c),0,0,0)

/* ---------------- weight prep: transpose to [N][K] + bf16 ---------------- */
__global__ __launch_bounds__(256) void prep_kernel(
    const float* __restrict__ in_w, const float* __restrict__ xp_w,
    const float* __restrict__ dt_w, const float* __restrict__ out_w,
    u16* __restrict__ WT1, u16* __restrict__ WT2, u16* __restrict__ WT3){
  int idx = blockIdx.x*256 + threadIdx.x;
  const int n1 = NLAYERS*512*128, n2 = NLAYERS*288*256, n3 = NLAYERS*128*256;
  if (idx < n1){
    int l = idx/(512*128), r = idx%(512*128), n = r/128, k = r%128;
    WT1[idx] = f2bf(in_w[((size_t)l*128 + k)*512 + n]);
  } else if (idx < n1+n2){
    int t = idx-n1; int l=t/(288*256), r=t%(288*256), n=r/256, k=r%256;
    float v = (n<32) ? xp_w[((size_t)l*256+k)*32 + n]
                     : dt_w[((size_t)l*256+k)*256 + (n-32)];
    WT2[t] = f2bf(v);
  } else if (idx < n1+n2+n3){
    int t = idx-n1-n2; int l=t/(128*256), r=t%(128*256), n=r/256, k=r%256;
    WT3[t] = f2bf(out_w[((size_t)l*256+k)*128 + n]);
  }
}

/* ------- embedding: h = x @ emb_w + emb_b, write tiled bf16 Hb ----------- */
__global__ __launch_bounds__(256) void emb_kernel(
    const float* __restrict__ x, const float* __restrict__ ew,
    const float* __restrict__ eb, u16* __restrict__ Hb, size_t cs){
  int idx = blockIdx.x*256 + threadIdx.x;
  int m = idx >> 7, d = idx & 127;
  float s = eb[d];
  #pragma unroll
  for (int k=0;k<16;++k) s += x[(size_t)m*16+k]*ew[k*128+d];
  Hb[(size_t)(d>>4)*cs + (size_t)m*16 + (d&15)] = f2bf(s);
}

/* -- GEMM1: R=4 rows/wave, half-split, prefetch; tiled loads/stores ------- */
__global__ __launch_bounds__(256) void gemm1_kernel(
    const u16* __restrict__ Hb, const u16* __restrict__ WT,
    const float* __restrict__ bias, u16* __restrict__ U, u16* __restrict__ ZS,
    size_t cs){
  const int lane = threadIdx.x & 63, wave = threadIdx.x >> 6;
  const int half = blockIdx.x & 1;
  const int m0 = (blockIdx.x >> 1)*256 + wave*64;
  const int lr = lane & 15, kg = lane >> 4;
  bf16x8 hfrag[4][4];
  #pragma unroll
  for (int g=0; g<4; ++g)
    #pragma unroll
    for (int f=0; f<4; ++f)
      hfrag[g][f] = *(const bf16x8*)(Hb + (size_t)((kg>>1)+2*f)*cs
                                     + (size_t)(m0+g*16+lr)*16 + (kg&1)*8);
  u16* const dst = half ? ZS : U;
  const u16* wrow = WT + (size_t)(half*256+lr)*128 + kg*8;
  bf16x8 wv[4];
  #pragma unroll
  for (int f=0; f<4; ++f) wv[f] = *(const bf16x8*)(wrow + f*32);
  #pragma unroll
  for (int nn=0; nn<16; ++nn){
    bf16x8 wn[4];
    if (nn < 15){
      const u16* wr2 = wrow + (size_t)(nn+1)*16*128;
      #pragma unroll
      for (int f=0; f<4; ++f) wn[f] = *(const bf16x8*)(wr2 + f*32);
    }
    f32x4 acc[4];
    #pragma unroll
    for (int g=0; g<4; ++g){
      acc[g] = (f32x4){0.f,0.f,0.f,0.f};
      #pragma unroll
      for (int f=0; f<4; ++f) acc[g] = MFMA16(wv[f], hfrag[g][f], acc[g]);
    }
    float4 bs4 = *(const float4*)(bias + half*256 + nn*16 + kg*4);
    #pragma unroll
    for (int g=0; g<4; ++g){
      ushort4 uv;
      uv.x = f2bf(siluf(acc[g][0]+bs4.x));
      uv.y = f2bf(siluf(acc[g][1]+bs4.y));
      uv.z = f2bf(siluf(acc[g][2]+bs4.z));
      uv.w = f2bf(siluf(acc[g][3]+bs4.w));
      *(ushort4*)(dst + (size_t)nn*cs + (size_t)(m0+g*16+lr)*16 + kg*4) = uv;
    }
    #pragma unroll
    for (int f=0; f<4; ++f) wv[f] = wn[f];
  }
}

/* -- GEMM2: R=2 rows/wave, prefetch; B(f32|bf16), C bf16, DT bf16 --------- */
template<int BF>
__global__ __launch_bounds__(256) void gemm2_kernel(
    const u16* __restrict__ Uin, const u16* __restrict__ WT,
    const float* __restrict__ xpb, const float* __restrict__ dtb,
    void* __restrict__ Bp, u16* __restrict__ Cb, u16* __restrict__ DT,
    size_t cs){
  const int lane = threadIdx.x & 63, wave = threadIdx.x >> 6;
  const int m0 = blockIdx.x*128 + wave*32;
  const int lr = lane & 15, kg = lane >> 4;
  bf16x8 hfrag[2][8];
  #pragma unroll
  for (int g=0; g<2; ++g)
    #pragma unroll
    for (int f=0; f<8; ++f)
      hfrag[g][f] = *(const bf16x8*)(Uin + (size_t)((kg>>1)+2*f)*cs
                                     + (size_t)(m0+g*16+lr)*16 + (kg&1)*8);
  const u16* wrow = WT + (size_t)lr*256 + kg*8;
  bf16x8 wv[8];
  #pragma unroll
  for (int f=0; f<8; ++f) wv[f] = *(const bf16x8*)(wrow + f*32);
  #pragma unroll
  for (int nn=0; nn<18; ++nn){
    bf16x8 wn[8];
    if (nn < 17){
      const u16* wr2 = wrow + (size_t)(nn+1)*16*256;
      #pragma unroll
      for (int f=0; f<8; ++f) wn[f] = *(const bf16x8*)(wr2 + f*32);
    }
    f32x4 acc[2];
    #pragma unroll
    for (int g=0; g<2; ++g){
      acc[g] = (f32x4){0.f,0.f,0.f,0.f};
      #pragma unroll
      for (int f=0; f<8; ++f) acc[g] = MFMA16(wv[f], hfrag[g][f], acc[g]);
    }
    const int col0 = nn*16 + kg*4;
    if (nn == 0){                                    /* B: cols 0..15 */
      float4 bs4 = *(const float4*)(xpb + col0);
      #pragma unroll
      for (int g=0; g<2; ++g){
        if (BF){
          float4 ov;
          ov.x = acc[g][0]+bs4.x; ov.y = acc[g][1]+bs4.y;
          ov.z = acc[g][2]+bs4.z; ov.w = acc[g][3]+bs4.w;
          *(float4*)((float*)Bp + (size_t)(m0+g*16+lr)*16 + kg*4) = ov;
        } else {
          ushort4 uv;
          uv.x = f2bf(acc[g][0]+bs4.x); uv.y = f2bf(acc[g][1]+bs4.y);
          uv.z = f2bf(acc[g][2]+bs4.z); uv.w = f2bf(acc[g][3]+bs4.w);
          *(ushort4*)((u16*)Bp + (size_t)(m0+g*16+lr)*16 + kg*4) = uv;
        }
      }
    } else if (nn == 1){                             /* C: cols 16..31 */
      float4 bs4 = *(const float4*)(xpb + col0);
      #pragma unroll
      for (int g=0; g<2; ++g){
        ushort4 uv;
        uv.x = f2bf(acc[g][0]+bs4.x); uv.y = f2bf(acc[g][1]+bs4.y);
        uv.z = f2bf(acc[g][2]+bs4.z); uv.w = f2bf(acc[g][3]+bs4.w);
        *(ushort4*)(Cb + (size_t)(m0+g*16+lr)*16 + (col0-16)) = uv;
      }
    } else {
      float4 bs4 = *(const float4*)(dtb + (col0-32));
      #pragma unroll
      for (int g=0; g<2; ++g){
        float v0=acc[g][0]+bs4.x, v1=acc[g][1]+bs4.y;
        float v2=acc[g][2]+bs4.z, v3=acc[g][3]+bs4.w;
        ushort4 uv;
        uv.x = f2bf(fmaxf(v0,0.f) + __logf(1.f + __expf(-fabsf(v0))));
        uv.y = f2bf(fmaxf(v1,0.f) + __logf(1.f + __expf(-fabsf(v1))));
        uv.z = f2bf(fmaxf(v2,0.f) + __logf(1.f + __expf(-fabsf(v2))));
        uv.w = f2bf(fmaxf(v3,0.f) + __logf(1.f + __expf(-fabsf(v3))));
        *(ushort4*)(DT + (size_t)(nn-2)*cs + (size_t)(m0+g*16+lr)*16 + kg*4) = uv;
      }
    }
    #pragma unroll
    for (int f=0; f<8; ++f) wv[f] = wn[f];
  }
}

/* depth-4 power tree: pw[i] = r^(i+1), i=0..15 */
static __device__ __forceinline__ void powtree(float r, float* pw){
  float p2=r*r, p3=p2*r, p4=p2*p2;
  float p5=p4*r, p6=p4*p2, p7=p4*p3, p8=p4*p4;
  pw[0]=r;  pw[1]=p2; pw[2]=p3; pw[3]=p4;
  pw[4]=p5; pw[5]=p6; pw[6]=p7; pw[7]=p8;
  pw[8]=p8*r;  pw[9]=p8*p2;  pw[10]=p8*p3;  pw[11]=p8*p4;
  pw[12]=p8*p5; pw[13]=p8*p6; pw[14]=p8*p7; pw[15]=p8*p8;
}

static __device__ __forceinline__ bool geo_check(const float* Alog, int c0, int c1){
  bool geo = true;
  #pragma unroll
  for (int i=0;i<16;++i){
    float A0 = -__expf(Alog[c0*16+i]);
    float A1 = -__expf(Alog[c1*16+i]);
    if (fabsf(A0+(float)(i+1))>1e-3f || fabsf(A1+(float)(i+1))>1e-3f) geo = false;
  }
  return geo;
}

/* SGH layout: [(b*nseg+seg)][17][256] u16 ; rows 0..15 = h, row 16 = sdt  */

/* ---- scan pass 1 (channel-paired, 128 thr): local scan + sum(dt) -------- */
template<int BF>
__global__ __launch_bounds__(128) void scan_p1(
    const u16* __restrict__ U, const u16* __restrict__ DT,
    const void* __restrict__ Bp, const float* __restrict__ Alog,
    u16* __restrict__ SGH, size_t cs, int nseg, int L){
  const int seg = blockIdx.x % nseg;
  const int b   = blockIdx.x / nseg;
  const int t   = threadIdx.x;
  const int c0  = 2*t, c1 = 2*t+1;
  const size_t poff = (size_t)(c0>>4)*cs + (c0&15);
  const bool geo = geo_check(Alog, c0, c1);
  float h0[16], h1[16];
  #pragma unroll
  for (int i=0;i<16;++i){ h0[i]=0.f; h1[i]=0.f; }
  float sdt0 = 0.f, sdt1 = 0.f;
  const size_t mbase = (size_t)b*SEQ + (size_t)seg*L;
  if (geo){
    for (int tt=0;tt<L;++tt){
      const size_t m = mbase + tt;
      u32 uu = *(const u32*)(U  + poff + m*16);
      u32 dd = *(const u32*)(DT + poff + m*16);
      float u0 = bf2f((u16)uu), u1 = bf2f((u16)(uu>>16));
      float d0 = bf2f((u16)dd), d1 = bf2f((u16)(dd>>16));
      float Bv[16];
      if (BF){
        const float* bp = (const float*)Bp + m*16;
        #pragma unroll
        for (int i=0;i<16;++i) Bv[i] = bp[i];
      } else {
        const u16* bp = (const u16*)Bp + m*16;
        #pragma unroll
        for (int i=0;i<16;++i) Bv[i] = bf2f(bp[i]);
      }
      float du0 = d0*u0, du1 = d1*u1;
      sdt0 += d0; sdt1 += d1;
      float r0 = exp2f(-1.44269504f*d0);
      float r1 = exp2f(-1.44269504f*d1);
      float pw0[16], pw1[16]; powtree(r0, pw0); powtree(r1, pw1);
      #pragma unroll
      for (int i=0;i<16;++i){
        h0[i] = h0[i]*pw0[i] + du0*Bv[i];
        h1[i] = h1[i]*pw1[i] + du1*Bv[i];
      }
    }
  } else {
    float a20[16], a21[16];
    #pragma unroll
    for (int i=0;i<16;++i){
      a20[i] = -__expf(Alog[c0*16+i]) * 1.44269504f;
      a21[i] = -__expf(Alog[c1*16+i]) * 1.44269504f;
    }
    for (int tt=0;tt<L;++tt){
      const size_t m = mbase + tt;
      u32 uu = *(const u32*)(U  + poff + m*16);
      u32 dd = *(const u32*)(DT + poff + m*16);
      float u0 = bf2f((u16)uu), u1 = bf2f((u16)(uu>>16));
      float d0 = bf2f((u16)dd), d1 = bf2f((u16)(dd>>16));
      float Bv[16];
      if (BF){
        const float* bp = (const float*)Bp + m*16;
        #pragma unroll
        for (int i=0;i<16;++i) Bv[i] = bp[i];
      } else {
        const u16* bp = (const u16*)Bp + m*16;
        #pragma unroll
        for (int i=0;i<16;++i) Bv[i] = bf2f(bp[i]);
      }
      float du0 = d0*u0, du1 = d1*u1;
      sdt0 += d0; sdt1 += d1;
      #pragma unroll
      for (int i=0;i<16;++i){
        h0[i] = h0[i]*exp2f(d0*a20[i]) + du0*Bv[i];
        h1[i] = h1[i]*exp2f(d1*a21[i]) + du1*Bv[i];
      }
    }
  }
  const size_t kb = ((size_t)b*nseg+seg);
  #pragma unroll
  for (int i=0;i<16;++i){
    u32 pk = (u32)f2bf(h0[i]) | ((u32)f2bf(h1[i]) << 16);
    *(u32*)(SGH + (kb*17+i)*256 + c0) = pk;
  }
  u32 ps = (u32)f2bf(sdt0) | ((u32)f2bf(sdt1) << 16);
  *(u32*)(SGH + (kb*17+16)*256 + c0) = ps;
}

/* ---------- scan pass 2: combine; SGH rows 0..15 <- h0 per segment ------- */
__global__ __launch_bounds__(256) void scan_p2(
    u16* __restrict__ SGH, const float* __restrict__ Alog, int nseg){
  const int i = blockIdx.x & 15, b = blockIdx.x >> 4, c = threadIdx.x;
  const float a2 = -__expf(Alog[c*16+i]) * 1.44269504f;
  float h = 0.f;
  for (int s=0;s<nseg;++s){
    const size_t kb = ((size_t)b*nseg+s);
    float sdt = bf2f(SGH[(kb*17+16)*256 + c]);
    size_t k = (kb*17+i)*256 + c;
    float hl = bf2f(SGH[k]);
    SGH[k] = f2bf(h);
    h = h*exp2f(sdt*a2) + hl;
  }
}

/* ---- scan pass 3 (channel-paired, 128 thr): re-scan, emit ys ------------ */
template<int BF>
__global__ __launch_bounds__(128) void scan_p3(
    u16* __restrict__ UY, const u16* __restrict__ DT, const void* __restrict__ Bp,
    const u16* __restrict__ Cb, const u16* __restrict__ ZS,
    const float* __restrict__ Alog, const float* __restrict__ Dp,
    const u16* __restrict__ SGH, size_t cs, int nseg, int L){
  const int seg = blockIdx.x % nseg;
  const int b   = blockIdx.x / nseg;
  const int t   = threadIdx.x;
  const int c0  = 2*t, c1 = 2*t+1;
  const size_t poff = (size_t)(c0>>4)*cs + (c0&15);
  const bool geo = geo_check(Alog, c0, c1);
  const float Dv0 = Dp[c0], Dv1 = Dp[c1];
  const size_t kb = ((size_t)b*nseg+seg);
  float h0[16], h1[16];
  #pragma unroll
  for (int i=0;i<16;++i){
    u32 hh = *(const u32*)(SGH + (kb*17+i)*256 + c0);
    h0[i] = bf2f((u16)hh); h1[i] = bf2f((u16)(hh>>16));
  }
  const size_t mbase = (size_t)b*SEQ + (size_t)seg*L;
  if (geo){
    for (int tt=0;tt<L;++tt){
      const size_t m = mbase + tt;
      u32 uu = *(const u32*)(UY + poff + m*16);
      u32 dd = *(const u32*)(DT + poff + m*16);
      u32 zz = *(const u32*)(ZS + poff + m*16);
      float u0 = bf2f((u16)uu), u1 = bf2f((u16)(uu>>16));
      float d0 = bf2f((u16)dd), d1 = bf2f((u16)(dd>>16));
      float z0 = bf2f((u16)zz), z1 = bf2f((u16)(zz>>16));
      float Bv[16], Cv[16];
      if (BF){
        const float* bp = (const float*)Bp + m*16;
        #pragma unroll
        for (int i=0;i<16;++i) Bv[i] = bp[i];
      } else {
        const u16* bp = (const u16*)Bp + m*16;
        #pragma unroll
        for (int i=0;i<16;++i) Bv[i] = bf2f(bp[i]);
      }
      {
        const u16* cp = Cb + m*16;
        #pragma unroll
        for (int i=0;i<16;++i) Cv[i] = bf2f(cp[i]);
      }
      float du0 = d0*u0, du1 = d1*u1;
      float r0 = exp2f(-1.44269504f*d0);
      float r1 = exp2f(-1.44269504f*d1);
      float pw0[16], pw1[16]; powtree(r0, pw0); powtree(r1, pw1);
      float s0 = 0.f, s1 = 0.f;
      #pragma unroll
      for (int i=0;i<16;++i){
        h0[i] = h0[i]*pw0[i] + du0*Bv[i];
        s0 += h0[i]*Cv[i];
        h1[i] = h1[i]*pw1[i] + du1*Bv[i];
        s1 += h1[i]*Cv[i];
      }
      float y0 = (s0 + Dv0*u0)*z0;
      float y1 = (s1 + Dv1*u1)*z1;
      u32 pk = (u32)f2bf(y0) | ((u32)f2bf(y1) << 16);
      *(u32*)(UY + poff + m*16) = pk;
    }
  } else {
    float a20[16], a21[16];
    #pragma unroll
    for (int i=0;i<16;++i){
      a20[i] = -__expf(Alog[c0*16+i]) * 1.44269504f;
      a21[i] = -__expf(Alog[c1*16+i]) * 1.44269504f;
    }
    for (int tt=0;tt<L;++tt){
      const size_t m = mbase + tt;
      u32 uu = *(const u32*)(UY + poff + m*16);
      u32 dd = *(const u32*)(DT + poff + m*16);
      u32 zz = *(const u32*)(ZS + poff + m*16);
      float u0 = bf2f((u16)uu), u1 = bf2f((u16)(uu>>16));
      float d0 = bf2f((u16)dd), d1 = bf2f((u16)(dd>>16));
      float z0 = bf2f((u16)zz), z1 = bf2f((u16)(zz>>16));
      float Bv[16], Cv[16];
      if (BF){
        const float* bp = (const float*)Bp + m*16;
        #pragma unroll
        for (int i=0;i<16;++i) Bv[i] = bp[i];
      } else {
        const u16* bp = (const u16*)Bp + m*16;
        #pragma unroll
        for (int i=0;i<16;++i) Bv[i] = bf2f(bp[i]);
      }
      {
        const u16* cp = Cb + m*16;
        #pragma unroll
        for (int i=0;i<16;++i) Cv[i] = bf2f(cp[i]);
      }
      float du0 = d0*u0, du1 = d1*u1;
      float s0 = 0.f, s1 = 0.f;
      #pragma unroll
      for (int i=0;i<16;++i){
        h0[i] = h0[i]*exp2f(d0*a20[i]) + du0*Bv[i];
        s0 += h0[i]*Cv[i];
        h1[i] = h1[i]*exp2f(d1*a21[i]) + du1*Bv[i];
        s1 += h1[i]*Cv[i];
      }
      float y0 = (s0 + Dv0*u0)*z0;
      float y1 = (s1 + Dv1*u1)*z1;
      u32 pk = (u32)f2bf(y0) | ((u32)f2bf(y1) << 16);
      *(u32*)(UY + poff + m*16) = pk;
    }
  }
}

/* --- GEMM3 + bf16 residual + LayerNorm, R=2, prefetch, all tiled --------- */
__global__ __launch_bounds__(256) void gemm3ln_kernel(
    const u16* __restrict__ YS, const u16* __restrict__ WT,
    const float* __restrict__ ob, const float* __restrict__ g,
    const float* __restrict__ bb, u16* __restrict__ Hb, size_t cs){
  const int lane = threadIdx.x & 63, wave = threadIdx.x >> 6;
  const int m0 = blockIdx.x*128 + wave*32;
  const int lr = lane & 15, kg = lane >> 4;
  bf16x8 hfrag[2][8];
  #pragma unroll
  for (int gg=0; gg<2; ++gg)
    #pragma unroll
    for (int f=0; f<8; ++f)
      hfrag[gg][f] = *(const bf16x8*)(YS + (size_t)((kg>>1)+2*f)*cs
                                      + (size_t)(m0+gg*16+lr)*16 + (kg&1)*8);
  const u16* wrow = WT + (size_t)lr*256 + kg*8;
  bf16x8 wv[8];
  #pragma unroll
  for (int f=0; f<8; ++f) wv[f] = *(const bf16x8*)(wrow + f*32);
  ushort4 xvp[2][8];
  float s[2] = {0.f,0.f}, q[2] = {0.f,0.f};
  #pragma unroll
  for (int n=0; n<8; ++n){
    bf16x8 wn[8];
    if (n < 7){
      const u16* wr2 = wrow + (size_t)(n+1)*16*256;
      #pragma unroll
      for (int f=0; f<8; ++f) wn[f] = *(const bf16x8*)(wr2 + f*32);
    }
    float4 bs4 = *(const float4*)(ob + n*16 + kg*4);
    #pragma unroll
    for (int gg=0; gg<2; ++gg){
      f32x4 acc = {0.f,0.f,0.f,0.f};
      #pragma unroll
      for (int f=0; f<8; ++f) acc = MFMA16(wv[f], hfrag[gg][f], acc);
      const size_t m = (size_t)(m0 + gg*16 + lr);
      ushort4 rs = *(const ushort4*)(Hb + (size_t)n*cs + m*16 + kg*4);
      float x0 = acc[0] + bs4.x + bf2f(rs.x);
      float x1 = acc[1] + bs4.y + bf2f(rs.y);
      float x2 = acc[2] + bs4.z + bf2f(rs.z);
      float x3 = acc[3] + bs4.w + bf2f(rs.w);
      s[gg] += (x0+x1)+(x2+x3);
      q[gg] += (x0*x0+x1*x1)+(x2*x2+x3*x3);
      ushort4 pv; pv.x=f2bf(x0); pv.y=f2bf(x1); pv.z=f2bf(x2); pv.w=f2bf(x3);
      xvp[gg][n] = pv;
    }
    #pragma unroll
    for (int f=0; f<8; ++f) wv[f] = wn[f];
  }
  #pragma unroll
  for (int gg=0; gg<2; ++gg){
    float ss = s[gg], qq = q[gg];
    ss += __shfl_xor(ss,16); qq += __shfl_xor(qq,16);
    ss += __shfl_xor(ss,32); qq += __shfl_xor(qq,32);
    float mu  = ss * 0.0078125f;
    float var = qq * 0.0078125f - mu*mu;
    float inv = rsqrtf(var + 1e-5f);
    const size_t m = (size_t)(m0 + gg*16 + lr);
    #pragma unroll
    for (int n=0;n<8;++n){
      float4 g4 = *(const float4*)(g  + n*16 + kg*4);
      float4 b4 = *(const float4*)(bb + n*16 + kg*4);
      ushort4 pv = xvp[gg][n];
      ushort4 uv;
      uv.x = f2bf((bf2f(pv.x)-mu)*inv*g4.x + b4.x);
      uv.y = f2bf((bf2f(pv.y)-mu)*inv*g4.y + b4.y);
      uv.z = f2bf((bf2f(pv.z)-mu)*inv*g4.z + b4.z);
      uv.w = f2bf((bf2f(pv.w)-mu)*inv*g4.w + b4.w);
      *(ushort4*)(Hb + (size_t)n*cs + m*16 + kg*4) = uv;
    }
  }
}

/* ---------------- two-stage mean over SEQ (tiled bf16 Hb) ---------------- */
__global__ __launch_bounds__(128) void pool1_kernel(
    const u16* __restrict__ Hb, float* __restrict__ PP, size_t cs){
  const int blk = blockIdx.x;
  const int tc = blk & 15, b = blk >> 4;
  const int d = threadIdx.x;
  const size_t coff = (size_t)(d>>4)*cs + (d&15);
  float s = 0.f;
  const size_t base = ((size_t)b*SEQ + tc*128);
  for (int t=0;t<128;++t) s += bf2f(Hb[coff + (base+t)*16]);
  PP[((size_t)b*16 + tc)*128 + d] = s;
}
__global__ __launch_bounds__(128) void pool2_kernel(
    const float* __restrict__ PP, float* __restrict__ P){
  const int b = blockIdx.x, d = threadIdx.x;
  float s = 0.f;
  #pragma unroll
  for (int tc=0;tc<16;++tc) s += PP[((size_t)b*16+tc)*128 + d];
  P[b*128 + d] = s * (1.f/SEQ);
}

/* ------------- head MLP + final formula (block per batch row) ----------- */
__global__ __launch_bounds__(64) void head_kernel(
    const float* __restrict__ P, const float* __restrict__ o1w,
    const float* __restrict__ o1b, const float* __restrict__ o2w,
    const float* __restrict__ o2b, const float* __restrict__ origins,
    float* __restrict__ out){
  const int b = blockIdx.x;
  const int j = threadIdx.x;
  float hv = o1b[j];
  #pragma unroll 4
  for (int d=0; d<128; ++d) hv += P[b*128+d]*o1w[d*64+j];
  hv = fmaxf(hv, 0.f);
  float p0 = hv*o2w[j*3+0], p1 = hv*o2w[j*3+1], p2 = hv*o2w[j*3+2];
  #pragma unroll
  for (int o=1;o<64;o<<=1){
    p0 += __shfl_xor(p0,o); p1 += __shfl_xor(p1,o); p2 += __shfl_xor(p2,o);
  }
  if (j == 0){
    float a = 2.f*sigm(p0 + o2b[0]);
    float bb = 2.f*sigm(p1 + o2b[1]);
    float c = 2.f*sigm(p2 + o2b[2]);
    const float* l1 = origins + ((size_t)b*SEQ + (SEQ-1))*16;
    const float* l2 = origins + ((size_t)b*SEQ + (SEQ-2))*16;
    float price=l1[0], ry_n=l1[1], ry_b=l2[1], gy_n=l1[2], gy_b=l2[2], ny_n=l1[3], ny_b=l2[3];
    out[b] = price*a*ry_n/ry_b*2.f*(bb*sigm(gy_n-gy_b) + c*sigm(ny_n-ny_b));
  }
}

extern "C" void kernel_launch(void* const* d_in, const int* in_sizes, int n_in,
                              void* d_out, int out_size, void* d_ws, size_t ws_size,
                              hipStream_t stream){
  const float* origins = (const float*)d_in[0];
  const float* x      = (const float*)d_in[1];
  const float* emb_w  = (const float*)d_in[2];
  const float* emb_b  = (const float*)d_in[3];
  const float* in_w   = (const float*)d_in[4];
  const float* in_b   = (const float*)d_in[5];
  const float* xp_w   = (const float*)d_in[6];
  const float* xp_b   = (const float*)d_in[7];
  const float* dt_w   = (const float*)d_in[8];
  const float* dt_b   = (const float*)d_in[9];
  const float* out_w  = (const float*)d_in[10];
  const float* out_b  = (const float*)d_in[11];
  const float* A_log  = (const float*)d_in[12];
  const float* Dp     = (const float*)d_in[13];
  const float* ln_g   = (const float*)d_in[14];
  const float* ln_b   = (const float*)d_in[15];
  const float* o1_w   = (const float*)d_in[16];
  const float* o1_b   = (const float*)d_in[17];
  const float* o2_w   = (const float*)d_in[18];
  const float* o2_b   = (const float*)d_in[19];
  float* outp = (float*)d_out;

  auto al = [](size_t b)->size_t{ return (b + 255) & ~(size_t)255; };
  const size_t wt1_b = al((size_t)NLAYERS*512*128*2);
  const size_t wt2_b = al((size_t)NLAYERS*288*256*2);
  const size_t wt3_b = al((size_t)NLAYERS*128*256*2);
  const size_t po_b  = al((size_t)B_SZ*128*4);
  const size_t pp_b  = al((size_t)B_SZ*16*128*4);
  const size_t fixed = wt1_b + wt2_b + wt3_b + po_b;

  /* cascade over (CB, NSEG, B dtype); prefer NSEG=32; PP unioned with SGH */
  int CB = 0, NSEG = 0, BCF = 0;
  size_t hb_b=0, u_b=0, b_b=0, c_b=0, sg_b=0;
  static const int cbc[7]  = {64,32,16,8,4,2,1};
  static const int nsc[4]  = {32,32,16,16};
  static const int bfc[4]  = {1,0,1,0};
  for (int i=0;i<7 && !CB;++i){
    int cb = cbc[i];
    size_t csz = (size_t)cb*SEQ*16;
    for (int k=0;k<4;++k){
      int ns = nsc[k], bf = bfc[k];
      size_t hbb = al(8*csz*2);
      size_t uu  = al(16*csz*2);
      size_t bB  = al(csz*(bf?4:2));
      size_t bC  = al(csz*2);
      size_t sg  = al((size_t)cb*ns*17*256*2);
      size_t ov  = (sg > pp_b) ? sg : pp_b;
      if (fixed + hbb + 3*uu + bB + bC + ov <= ws_size){
        CB=cb; NSEG=ns; BCF=bf; hb_b=hbb; u_b=uu; b_b=bB; c_b=bC; sg_b=ov; break;
      }
    }
  }
  if (!CB) return;

  char* ws = (char*)d_ws;
  size_t off = 0;
  auto take = [&](size_t bytes)->char*{ char* p = ws + off; off += bytes; return p; };
  u16*   WT1 = (u16*)take(wt1_b);
  u16*   WT2 = (u16*)take(wt2_b);
  u16*   WT3 = (u16*)take(wt3_b);
  float* PO  = (float*)take(po_b);
  u16*   Hb  = (u16*)take(hb_b);
  u16*   U   = (u16*)take(u_b);
  u16*   ZS  = (u16*)take(u_b);
  u16*   DT  = (u16*)take(u_b);
  void*  Bp  = (void*)take(b_b);
  u16*   Cb  = (u16*)take(c_b);
  u16*   SGH = (u16*)take(sg_b);
  float* PP  = (float*)SGH;                    /* disjoint lifetime */

  prep_kernel<<<3360, 256, 0, stream>>>(in_w, xp_w, dt_w, out_w, WT1, WT2, WT3);

  const int NC = B_SZ / CB;
  const int Mc = CB * SEQ;
  const int L  = SEQ / NSEG;
  const size_t cs = (size_t)Mc*16;
  for (int ci=0; ci<NC; ++ci){
    const int b0 = ci * CB;
    const size_t R0 = (size_t)b0 * SEQ;
    emb_kernel<<<(Mc*DMODEL)/256, 256, 0, stream>>>(x + R0*16, emb_w, emb_b, Hb, cs);
    for (int l=0;l<NLAYERS;++l){
      const float* Al = A_log + (size_t)l*DINNER*DSTATE;
      gemm1_kernel<<<(Mc/256)*2, 256, 0, stream>>>(Hb, WT1 + (size_t)l*512*128,
                                                   in_b + l*512, U, ZS, cs);
      if (BCF){
        gemm2_kernel<1><<<Mc/128, 256, 0, stream>>>(U, WT2 + (size_t)l*288*256,
                                                    xp_b + l*32, dt_b + l*256,
                                                    Bp, Cb, DT, cs);
        scan_p1<1><<<CB*NSEG, 128, 0, stream>>>(U, DT, Bp, Al, SGH, cs, NSEG, L);
        scan_p2<<<CB*16, 256, 0, stream>>>(SGH, Al, NSEG);
        scan_p3<1><<<CB*NSEG, 128, 0, stream>>>(U, DT, Bp, Cb, ZS, Al,
                                                Dp + l*DINNER, SGH, cs, NSEG, L);
      } else {
        gemm2_kernel<0><<<Mc/128, 256, 0, stream>>>(U, WT2 + (size_t)l*288*256,
                                                    xp_b + l*32, dt_b + l*256,
                                                    Bp, Cb, DT, cs);
        scan_p1<0><<<CB*NSEG, 128, 0, stream>>>(U, DT, Bp, Al, SGH, cs, NSEG, L);
        scan_p2<<<CB*16, 256, 0, stream>>>(SGH, Al, NSEG);
        scan_p3<0><<<CB*NSEG, 128, 0, stream>>>(U, DT, Bp, Cb, ZS, Al,
                                                Dp + l*DINNER, SGH, cs, NSEG, L);
      }
      gemm3ln_kernel<<<Mc/128, 256, 0, stream>>>(U, WT3 + (size_t)l*128*256,
                                                 out_b + l*128, ln_g + l*128,
                                                 ln_b + l*128, Hb, cs);
    }
    pool1_kernel<<<CB*16, 128, 0, stream>>>(Hb, PP, cs);
    pool2_kernel<<<CB, 128, 0, stream>>>(PP, PO + (size_t)b0*128);
  }
  head_kernel<<<B_SZ, 64, 0, stream>>>(PO, o1_w, o1_b, o2_w, o2_b, origins, outp);
}

// Round 12
// 1786.720 us; speedup vs baseline: 1.1139x; 1.1139x over previous
//
#include <hip/hip_runtime.h>
#include <hip/hip_bf16.h>
#include <math.h>

#define B_SZ    64
#define SEQ     2048
#define DMODEL  128
#define DINNER  256
#define DSTATE  16
#define NLAYERS 5

typedef unsigned short u16;
typedef unsigned int   u32;
typedef __attribute__((ext_vector_type(8))) short bf16x8;
typedef __attribute__((ext_vector_type(4))) float f32x4;

static __device__ __forceinline__ float bf2f(u16 u){
  union { unsigned u; float f; } a; a.u = ((unsigned)u) << 16; return a.f;
}
static __device__ __forceinline__ u16 f2bf(float f){
  union { float f; unsigned u; } a; a.f = f;
  unsigned r = a.u + 0x7fffu + ((a.u >> 16) & 1u);
  return (u16)(r >> 16);
}
static __device__ __forceinline__ float sigm(float x){ return 1.f/(1.f+__expf(-x)); }
static __device__ __forceinline__ float siluf(float x){ return x/(1.f+__expf(-x)); }

#define MFMA16(a,b,c) __builtin_amdgcn_mfma_f32_16x16x32_bf16((a),(b),(c),0,0,0)

/* ---------------- weight prep: transpose to [N][K] + bf16 ---------------- */
__global__ __launch_bounds__(256) void prep_kernel(
    const float* __restrict__ in_w, const float* __restrict__ xp_w,
    const float* __restrict__ dt_w, const float* __restrict__ out_w,
    u16* __restrict__ WT1, u16* __restrict__ WT2, u16* __restrict__ WT3){
  int idx = blockIdx.x*256 + threadIdx.x;
  const int n1 = NLAYERS*512*128, n2 = NLAYERS*288*256, n3 = NLAYERS*128*256;
  if (idx < n1){
    int l = idx/(512*128), r = idx%(512*128), n = r/128, k = r%128;
    WT1[idx] = f2bf(in_w[((size_t)l*128 + k)*512 + n]);
  } else if (idx < n1+n2){
    int t = idx-n1; int l=t/(288*256), r=t%(288*256), n=r/256, k=r%256;
    float v = (n<32) ? xp_w[((size_t)l*256+k)*32 + n]
                     : dt_w[((size_t)l*256+k)*256 + (n-32)];
    WT2[t] = f2bf(v);
  } else if (idx < n1+n2+n3){
    int t = idx-n1-n2; int l=t/(128*256), r=t%(128*256), n=r/256, k=r%256;
    WT3[t] = f2bf(out_w[((size_t)l*256+k)*128 + n]);
  }
}

/* ------- embedding: h = x @ emb_w + emb_b, write tiled bf16 Hb ----------- */
__global__ __launch_bounds__(256) void emb_kernel(
    const float* __restrict__ x, const float* __restrict__ ew,
    const float* __restrict__ eb, u16* __restrict__ Hb, size_t cs){
  int idx = blockIdx.x*256 + threadIdx.x;
  int m = idx >> 7, d = idx & 127;
  float s = eb[d];
  #pragma unroll
  for (int k=0;k<16;++k) s += x[(size_t)m*16+k]*ew[k*128+d];
  Hb[(size_t)(d>>4)*cs + (size_t)m*16 + (d&15)] = f2bf(s);
}

/* -- GEMM1: R=4 rows/wave, half-split, prefetch; tiled loads/stores ------- */
__global__ __launch_bounds__(256) void gemm1_kernel(
    const u16* __restrict__ Hb, const u16* __restrict__ WT,
    const float* __restrict__ bias, u16* __restrict__ U, u16* __restrict__ ZS,
    size_t cs){
  const int lane = threadIdx.x & 63, wave = threadIdx.x >> 6;
  const int half = blockIdx.x & 1;
  const int m0 = (blockIdx.x >> 1)*256 + wave*64;
  const int lr = lane & 15, kg = lane >> 4;
  bf16x8 hfrag[4][4];
  #pragma unroll
  for (int g=0; g<4; ++g)
    #pragma unroll
    for (int f=0; f<4; ++f)
      hfrag[g][f] = *(const bf16x8*)(Hb + (size_t)((kg>>1)+2*f)*cs
                                     + (size_t)(m0+g*16+lr)*16 + (kg&1)*8);
  u16* const dst = half ? ZS : U;
  const u16* wrow = WT + (size_t)(half*256+lr)*128 + kg*8;
  bf16x8 wv[4];
  #pragma unroll
  for (int f=0; f<4; ++f) wv[f] = *(const bf16x8*)(wrow + f*32);
  #pragma unroll
  for (int nn=0; nn<16; ++nn){
    bf16x8 wn[4];
    if (nn < 15){
      const u16* wr2 = wrow + (size_t)(nn+1)*16*128;
      #pragma unroll
      for (int f=0; f<4; ++f) wn[f] = *(const bf16x8*)(wr2 + f*32);
    }
    f32x4 acc[4];
    #pragma unroll
    for (int g=0; g<4; ++g){
      acc[g] = (f32x4){0.f,0.f,0.f,0.f};
      #pragma unroll
      for (int f=0; f<4; ++f) acc[g] = MFMA16(wv[f], hfrag[g][f], acc[g]);
    }
    float4 bs4 = *(const float4*)(bias + half*256 + nn*16 + kg*4);
    #pragma unroll
    for (int g=0; g<4; ++g){
      ushort4 uv;
      uv.x = f2bf(siluf(acc[g][0]+bs4.x));
      uv.y = f2bf(siluf(acc[g][1]+bs4.y));
      uv.z = f2bf(siluf(acc[g][2]+bs4.z));
      uv.w = f2bf(siluf(acc[g][3]+bs4.w));
      *(ushort4*)(dst + (size_t)nn*cs + (size_t)(m0+g*16+lr)*16 + kg*4) = uv;
    }
    #pragma unroll
    for (int f=0; f<4; ++f) wv[f] = wn[f];
  }
}

/* -- GEMM2: R=2 rows/wave, prefetch; B(f32|bf16), C bf16, DT bf16 --------- */
template<int BF>
__global__ __launch_bounds__(256) void gemm2_kernel(
    const u16* __restrict__ Uin, const u16* __restrict__ WT,
    const float* __restrict__ xpb, const float* __restrict__ dtb,
    void* __restrict__ Bp, u16* __restrict__ Cb, u16* __restrict__ DT,
    size_t cs){
  const int lane = threadIdx.x & 63, wave = threadIdx.x >> 6;
  const int m0 = blockIdx.x*128 + wave*32;
  const int lr = lane & 15, kg = lane >> 4;
  bf16x8 hfrag[2][8];
  #pragma unroll
  for (int g=0; g<2; ++g)
    #pragma unroll
    for (int f=0; f<8; ++f)
      hfrag[g][f] = *(const bf16x8*)(Uin + (size_t)((kg>>1)+2*f)*cs
                                     + (size_t)(m0+g*16+lr)*16 + (kg&1)*8);
  const u16* wrow = WT + (size_t)lr*256 + kg*8;
  bf16x8 wv[8];
  #pragma unroll
  for (int f=0; f<8; ++f) wv[f] = *(const bf16x8*)(wrow + f*32);
  #pragma unroll
  for (int nn=0; nn<18; ++nn){
    bf16x8 wn[8];
    if (nn < 17){
      const u16* wr2 = wrow + (size_t)(nn+1)*16*256;
      #pragma unroll
      for (int f=0; f<8; ++f) wn[f] = *(const bf16x8*)(wr2 + f*32);
    }
    f32x4 acc[2];
    #pragma unroll
    for (int g=0; g<2; ++g){
      acc[g] = (f32x4){0.f,0.f,0.f,0.f};
      #pragma unroll
      for (int f=0; f<8; ++f) acc[g] = MFMA16(wv[f], hfrag[g][f], acc[g]);
    }
    const int col0 = nn*16 + kg*4;
    if (nn == 0){                                    /* B: cols 0..15 */
      float4 bs4 = *(const float4*)(xpb + col0);
      #pragma unroll
      for (int g=0; g<2; ++g){
        if (BF){
          float4 ov;
          ov.x = acc[g][0]+bs4.x; ov.y = acc[g][1]+bs4.y;
          ov.z = acc[g][2]+bs4.z; ov.w = acc[g][3]+bs4.w;
          *(float4*)((float*)Bp + (size_t)(m0+g*16+lr)*16 + kg*4) = ov;
        } else {
          ushort4 uv;
          uv.x = f2bf(acc[g][0]+bs4.x); uv.y = f2bf(acc[g][1]+bs4.y);
          uv.z = f2bf(acc[g][2]+bs4.z); uv.w = f2bf(acc[g][3]+bs4.w);
          *(ushort4*)((u16*)Bp + (size_t)(m0+g*16+lr)*16 + kg*4) = uv;
        }
      }
    } else if (nn == 1){                             /* C: cols 16..31 */
      float4 bs4 = *(const float4*)(xpb + col0);
      #pragma unroll
      for (int g=0; g<2; ++g){
        ushort4 uv;
        uv.x = f2bf(acc[g][0]+bs4.x); uv.y = f2bf(acc[g][1]+bs4.y);
        uv.z = f2bf(acc[g][2]+bs4.z); uv.w = f2bf(acc[g][3]+bs4.w);
        *(ushort4*)(Cb + (size_t)(m0+g*16+lr)*16 + (col0-16)) = uv;
      }
    } else {
      float4 bs4 = *(const float4*)(dtb + (col0-32));
      #pragma unroll
      for (int g=0; g<2; ++g){
        float v0=acc[g][0]+bs4.x, v1=acc[g][1]+bs4.y;
        float v2=acc[g][2]+bs4.z, v3=acc[g][3]+bs4.w;
        ushort4 uv;
        uv.x = f2bf(fmaxf(v0,0.f) + __logf(1.f + __expf(-fabsf(v0))));
        uv.y = f2bf(fmaxf(v1,0.f) + __logf(1.f + __expf(-fabsf(v1))));
        uv.z = f2bf(fmaxf(v2,0.f) + __logf(1.f + __expf(-fabsf(v2))));
        uv.w = f2bf(fmaxf(v3,0.f) + __logf(1.f + __expf(-fabsf(v3))));
        *(ushort4*)(DT + (size_t)(nn-2)*cs + (size_t)(m0+g*16+lr)*16 + kg*4) = uv;
      }
    }
    #pragma unroll
    for (int f=0; f<8; ++f) wv[f] = wn[f];
  }
}

/* depth-4 power tree: pw[i] = r^(i+1), i=0..15 */
static __device__ __forceinline__ void powtree(float r, float* pw){
  float p2=r*r, p3=p2*r, p4=p2*p2;
  float p5=p4*r, p6=p4*p2, p7=p4*p3, p8=p4*p4;
  pw[0]=r;  pw[1]=p2; pw[2]=p3; pw[3]=p4;
  pw[4]=p5; pw[5]=p6; pw[6]=p7; pw[7]=p8;
  pw[8]=p8*r;  pw[9]=p8*p2;  pw[10]=p8*p3;  pw[11]=p8*p4;
  pw[12]=p8*p5; pw[13]=p8*p6; pw[14]=p8*p7; pw[15]=p8*p8;
}

/* SGH layout: [(b*nseg+seg)][17][256] u16 ; rows 0..15 = h, row 16 = sdt  */

/* ---- scan pass 1 (256 thr, 1 ch/thread): local scan + sum(dt) ----------- */
template<int BF>
__global__ __launch_bounds__(256) void scan_p1(
    const u16* __restrict__ U, const u16* __restrict__ DT,
    const void* __restrict__ Bp, const float* __restrict__ Alog,
    u16* __restrict__ SGH, size_t cs, int nseg, int L){
  const int seg = blockIdx.x % nseg;
  const int b   = blockIdx.x / nseg;
  const int c   = threadIdx.x;
  const size_t coff = (size_t)(c>>4)*cs + (c&15);
  bool geo = true;
  #pragma unroll
  for (int i=0;i<16;++i){
    float A = -__expf(Alog[c*16+i]);
    if (fabsf(A + (float)(i+1)) > 1e-3f) geo = false;
  }
  float h[16];
  #pragma unroll
  for (int i=0;i<16;++i) h[i]=0.f;
  float sdt = 0.f;
  const size_t mbase = (size_t)b*SEQ + (size_t)seg*L;
  if (geo){
    #pragma unroll 2
    for (int t=0;t<L;++t){
      const size_t m = mbase + t;
      float u  = bf2f(U [coff + m*16]);
      float dt = bf2f(DT[coff + m*16]);
      float Bv[16];
      if (BF){
        const float* bp = (const float*)Bp + m*16;     /* wave-uniform */
        #pragma unroll
        for (int i=0;i<16;++i) Bv[i] = bp[i];
      } else {
        const u16* bp = (const u16*)Bp + m*16;
        #pragma unroll
        for (int i=0;i<16;++i) Bv[i] = bf2f(bp[i]);
      }
      float du = dt*u; sdt += dt;
      float r = exp2f(-1.44269504f*dt);
      float pw[16]; powtree(r, pw);
      #pragma unroll
      for (int i=0;i<16;++i) h[i] = h[i]*pw[i] + du*Bv[i];
    }
  } else {
    float a2[16];
    #pragma unroll
    for (int i=0;i<16;++i) a2[i] = -__expf(Alog[c*16+i]) * 1.44269504f;
    for (int t=0;t<L;++t){
      const size_t m = mbase + t;
      float u  = bf2f(U [coff + m*16]);
      float dt = bf2f(DT[coff + m*16]);
      float Bv[16];
      if (BF){
        const float* bp = (const float*)Bp + m*16;
        #pragma unroll
        for (int i=0;i<16;++i) Bv[i] = bp[i];
      } else {
        const u16* bp = (const u16*)Bp + m*16;
        #pragma unroll
        for (int i=0;i<16;++i) Bv[i] = bf2f(bp[i]);
      }
      float du = dt*u; sdt += dt;
      #pragma unroll
      for (int i=0;i<16;++i)
        h[i] = h[i]*exp2f(dt*a2[i]) + du*Bv[i];
    }
  }
  const size_t kb = ((size_t)b*nseg+seg);
  #pragma unroll
  for (int i=0;i<16;++i) SGH[(kb*17+i)*256 + c] = f2bf(h[i]);
  SGH[(kb*17+16)*256 + c] = f2bf(sdt);
}

/* ---------- scan pass 2: combine; SGH rows 0..15 <- h0 per segment ------- */
__global__ __launch_bounds__(256) void scan_p2(
    u16* __restrict__ SGH, const float* __restrict__ Alog, int nseg){
  const int i = blockIdx.x & 15, b = blockIdx.x >> 4, c = threadIdx.x;
  const float a2 = -__expf(Alog[c*16+i]) * 1.44269504f;
  float h = 0.f;
  for (int s=0;s<nseg;++s){
    const size_t kb = ((size_t)b*nseg+s);
    float sdt = bf2f(SGH[(kb*17+16)*256 + c]);
    size_t k = (kb*17+i)*256 + c;
    float hl = bf2f(SGH[k]);
    SGH[k] = f2bf(h);
    h = h*exp2f(sdt*a2) + hl;
  }
}

/* ---- scan pass 3 (256 thr, 1 ch/thread): re-scan, emit ys --------------- */
template<int BF>
__global__ __launch_bounds__(256) void scan_p3(
    u16* __restrict__ UY, const u16* __restrict__ DT, const void* __restrict__ Bp,
    const u16* __restrict__ Cb, const u16* __restrict__ ZS,
    const float* __restrict__ Alog, const float* __restrict__ Dp,
    const u16* __restrict__ SGH, size_t cs, int nseg, int L){
  const int seg = blockIdx.x % nseg;
  const int b   = blockIdx.x / nseg;
  const int c   = threadIdx.x;
  const size_t coff = (size_t)(c>>4)*cs + (c&15);
  bool geo = true;
  #pragma unroll
  for (int i=0;i<16;++i){
    float A = -__expf(Alog[c*16+i]);
    if (fabsf(A + (float)(i+1)) > 1e-3f) geo = false;
  }
  const float Dv = Dp[c];
  const size_t kb = ((size_t)b*nseg+seg);
  float h[16];
  #pragma unroll
  for (int i=0;i<16;++i) h[i] = bf2f(SGH[(kb*17+i)*256 + c]);
  const size_t mbase = (size_t)b*SEQ + (size_t)seg*L;
  if (geo){
    #pragma unroll 2
    for (int t=0;t<L;++t){
      const size_t m = mbase + t;
      float u  = bf2f(UY[coff + m*16]);
      float dt = bf2f(DT[coff + m*16]);
      float zs = bf2f(ZS[coff + m*16]);
      float Bv[16], Cv[16];
      if (BF){
        const float* bp = (const float*)Bp + m*16;     /* wave-uniform */
        #pragma unroll
        for (int i=0;i<16;++i) Bv[i] = bp[i];
      } else {
        const u16* bp = (const u16*)Bp + m*16;
        #pragma unroll
        for (int i=0;i<16;++i) Bv[i] = bf2f(bp[i]);
      }
      {
        const u16* cp = Cb + m*16;                     /* wave-uniform */
        #pragma unroll
        for (int i=0;i<16;++i) Cv[i] = bf2f(cp[i]);
      }
      float du = dt*u;
      float r = exp2f(-1.44269504f*dt);
      float pw[16]; powtree(r, pw);
      float s0=0.f, s1=0.f;
      #pragma unroll
      for (int i=0;i<8;++i){
        h[i] = h[i]*pw[i] + du*Bv[i];
        s0 += h[i]*Cv[i];
      }
      #pragma unroll
      for (int i=8;i<16;++i){
        h[i] = h[i]*pw[i] + du*Bv[i];
        s1 += h[i]*Cv[i];
      }
      float y = s0 + s1 + Dv*u;
      UY[coff + m*16] = f2bf(y*zs);
    }
  } else {
    float a2[16];
    #pragma unroll
    for (int i=0;i<16;++i) a2[i] = -__expf(Alog[c*16+i]) * 1.44269504f;
    for (int t=0;t<L;++t){
      const size_t m = mbase + t;
      float u  = bf2f(UY[coff + m*16]);
      float dt = bf2f(DT[coff + m*16]);
      float zs = bf2f(ZS[coff + m*16]);
      float Bv[16], Cv[16];
      if (BF){
        const float* bp = (const float*)Bp + m*16;
        #pragma unroll
        for (int i=0;i<16;++i) Bv[i] = bp[i];
      } else {
        const u16* bp = (const u16*)Bp + m*16;
        #pragma unroll
        for (int i=0;i<16;++i) Bv[i] = bf2f(bp[i]);
      }
      {
        const u16* cp = Cb + m*16;
        #pragma unroll
        for (int i=0;i<16;++i) Cv[i] = bf2f(cp[i]);
      }
      float du = dt*u;
      float s0=0.f;
      #pragma unroll
      for (int i=0;i<16;++i){
        h[i] = h[i]*exp2f(dt*a2[i]) + du*Bv[i];
        s0 += h[i]*Cv[i];
      }
      float y = s0 + Dv*u;
      UY[coff + m*16] = f2bf(y*zs);
    }
  }
}

/* --- GEMM3 + bf16 residual + LayerNorm, R=2, prefetch, all tiled --------- */
__global__ __launch_bounds__(256) void gemm3ln_kernel(
    const u16* __restrict__ YS, const u16* __restrict__ WT,
    const float* __restrict__ ob, const float* __restrict__ g,
    const float* __restrict__ bb, u16* __restrict__ Hb, size_t cs){
  const int lane = threadIdx.x & 63, wave = threadIdx.x >> 6;
  const int m0 = blockIdx.x*128 + wave*32;
  const int lr = lane & 15, kg = lane >> 4;
  bf16x8 hfrag[2][8];
  #pragma unroll
  for (int gg=0; gg<2; ++gg)
    #pragma unroll
    for (int f=0; f<8; ++f)
      hfrag[gg][f] = *(const bf16x8*)(YS + (size_t)((kg>>1)+2*f)*cs
                                      + (size_t)(m0+gg*16+lr)*16 + (kg&1)*8);
  const u16* wrow = WT + (size_t)lr*256 + kg*8;
  bf16x8 wv[8];
  #pragma unroll
  for (int f=0; f<8; ++f) wv[f] = *(const bf16x8*)(wrow + f*32);
  ushort4 xvp[2][8];
  float s[2] = {0.f,0.f}, q[2] = {0.f,0.f};
  #pragma unroll
  for (int n=0; n<8; ++n){
    bf16x8 wn[8];
    if (n < 7){
      const u16* wr2 = wrow + (size_t)(n+1)*16*256;
      #pragma unroll
      for (int f=0; f<8; ++f) wn[f] = *(const bf16x8*)(wr2 + f*32);
    }
    float4 bs4 = *(const float4*)(ob + n*16 + kg*4);
    #pragma unroll
    for (int gg=0; gg<2; ++gg){
      f32x4 acc = {0.f,0.f,0.f,0.f};
      #pragma unroll
      for (int f=0; f<8; ++f) acc = MFMA16(wv[f], hfrag[gg][f], acc);
      const size_t m = (size_t)(m0 + gg*16 + lr);
      ushort4 rs = *(const ushort4*)(Hb + (size_t)n*cs + m*16 + kg*4);
      float x0 = acc[0] + bs4.x + bf2f(rs.x);
      float x1 = acc[1] + bs4.y + bf2f(rs.y);
      float x2 = acc[2] + bs4.z + bf2f(rs.z);
      float x3 = acc[3] + bs4.w + bf2f(rs.w);
      s[gg] += (x0+x1)+(x2+x3);
      q[gg] += (x0*x0+x1*x1)+(x2*x2+x3*x3);
      ushort4 pv; pv.x=f2bf(x0); pv.y=f2bf(x1); pv.z=f2bf(x2); pv.w=f2bf(x3);
      xvp[gg][n] = pv;
    }
    #pragma unroll
    for (int f=0; f<8; ++f) wv[f] = wn[f];
  }
  #pragma unroll
  for (int gg=0; gg<2; ++gg){
    float ss = s[gg], qq = q[gg];
    ss += __shfl_xor(ss,16); qq += __shfl_xor(qq,16);
    ss += __shfl_xor(ss,32); qq += __shfl_xor(qq,32);
    float mu  = ss * 0.0078125f;
    float var = qq * 0.0078125f - mu*mu;
    float inv = rsqrtf(var + 1e-5f);
    const size_t m = (size_t)(m0 + gg*16 + lr);
    #pragma unroll
    for (int n=0;n<8;++n){
      float4 g4 = *(const float4*)(g  + n*16 + kg*4);
      float4 b4 = *(const float4*)(bb + n*16 + kg*4);
      ushort4 pv = xvp[gg][n];
      ushort4 uv;
      uv.x = f2bf((bf2f(pv.x)-mu)*inv*g4.x + b4.x);
      uv.y = f2bf((bf2f(pv.y)-mu)*inv*g4.y + b4.y);
      uv.z = f2bf((bf2f(pv.z)-mu)*inv*g4.z + b4.z);
      uv.w = f2bf((bf2f(pv.w)-mu)*inv*g4.w + b4.w);
      *(ushort4*)(Hb + (size_t)n*cs + m*16 + kg*4) = uv;
    }
  }
}

/* ---------------- two-stage mean over SEQ (tiled bf16 Hb) ---------------- */
__global__ __launch_bounds__(128) void pool1_kernel(
    const u16* __restrict__ Hb, float* __restrict__ PP, size_t cs){
  const int blk = blockIdx.x;
  const int tc = blk & 15, b = blk >> 4;
  const int d = threadIdx.x;
  const size_t coff = (size_t)(d>>4)*cs + (d&15);
  float s = 0.f;
  const size_t base = ((size_t)b*SEQ + tc*128);
  for (int t=0;t<128;++t) s += bf2f(Hb[coff + (base+t)*16]);
  PP[((size_t)b*16 + tc)*128 + d] = s;
}
__global__ __launch_bounds__(128) void pool2_kernel(
    const float* __restrict__ PP, float* __restrict__ P){
  const int b = blockIdx.x, d = threadIdx.x;
  float s = 0.f;
  #pragma unroll
  for (int tc=0;tc<16;++tc) s += PP[((size_t)b*16+tc)*128 + d];
  P[b*128 + d] = s * (1.f/SEQ);
}

/* ------------- head MLP + final formula (block per batch row) ----------- */
__global__ __launch_bounds__(64) void head_kernel(
    const float* __restrict__ P, const float* __restrict__ o1w,
    const float* __restrict__ o1b, const float* __restrict__ o2w,
    const float* __restrict__ o2b, const float* __restrict__ origins,
    float* __restrict__ out){
  const int b = blockIdx.x;
  const int j = threadIdx.x;
  float hv = o1b[j];
  #pragma unroll 4
  for (int d=0; d<128; ++d) hv += P[b*128+d]*o1w[d*64+j];
  hv = fmaxf(hv, 0.f);
  float p0 = hv*o2w[j*3+0], p1 = hv*o2w[j*3+1], p2 = hv*o2w[j*3+2];
  #pragma unroll
  for (int o=1;o<64;o<<=1){
    p0 += __shfl_xor(p0,o); p1 += __shfl_xor(p1,o); p2 += __shfl_xor(p2,o);
  }
  if (j == 0){
    float a = 2.f*sigm(p0 + o2b[0]);
    float bb = 2.f*sigm(p1 + o2b[1]);
    float c = 2.f*sigm(p2 + o2b[2]);
    const float* l1 = origins + ((size_t)b*SEQ + (SEQ-1))*16;
    const float* l2 = origins + ((size_t)b*SEQ + (SEQ-2))*16;
    float price=l1[0], ry_n=l1[1], ry_b=l2[1], gy_n=l1[2], gy_b=l2[2], ny_n=l1[3], ny_b=l2[3];
    out[b] = price*a*ry_n/ry_b*2.f*(bb*sigm(gy_n-gy_b) + c*sigm(ny_n-ny_b));
  }
}

extern "C" void kernel_launch(void* const* d_in, const int* in_sizes, int n_in,
                              void* d_out, int out_size, void* d_ws, size_t ws_size,
                              hipStream_t stream){
  const float* origins = (const float*)d_in[0];
  const float* x      = (const float*)d_in[1];
  const float* emb_w  = (const float*)d_in[2];
  const float* emb_b  = (const float*)d_in[3];
  const float* in_w   = (const float*)d_in[4];
  const float* in_b   = (const float*)d_in[5];
  const float* xp_w   = (const float*)d_in[6];
  const float* xp_b   = (const float*)d_in[7];
  const float* dt_w   = (const float*)d_in[8];
  const float* dt_b   = (const float*)d_in[9];
  const float* out_w  = (const float*)d_in[10];
  const float* out_b  = (const float*)d_in[11];
  const float* A_log  = (const float*)d_in[12];
  const float* Dp     = (const float*)d_in[13];
  const float* ln_g   = (const float*)d_in[14];
  const float* ln_b   = (const float*)d_in[15];
  const float* o1_w   = (const float*)d_in[16];
  const float* o1_b   = (const float*)d_in[17];
  const float* o2_w   = (const float*)d_in[18];
  const float* o2_b   = (const float*)d_in[19];
  float* outp = (float*)d_out;

  auto al = [](size_t b)->size_t{ return (b + 255) & ~(size_t)255; };
  const size_t wt1_b = al((size_t)NLAYERS*512*128*2);
  const size_t wt2_b = al((size_t)NLAYERS*288*256*2);
  const size_t wt3_b = al((size_t)NLAYERS*128*256*2);
  const size_t po_b  = al((size_t)B_SZ*128*4);
  const size_t pp_b  = al((size_t)B_SZ*16*128*4);
  const size_t fixed = wt1_b + wt2_b + wt3_b + po_b;

  /* cascade over (CB, NSEG, B dtype); prefer NSEG=32 + f32 B; PP∪SGH */
  int CB = 0, NSEG = 0, BCF = 0;
  size_t hb_b=0, u_b=0, b_b=0, c_b=0, sg_b=0;
  static const int cbc[7]  = {64,32,16,8,4,2,1};
  static const int nsc[4]  = {32,32,16,16};
  static const int bfc[4]  = {1,0,1,0};
  for (int i=0;i<7 && !CB;++i){
    int cb = cbc[i];
    size_t csz = (size_t)cb*SEQ*16;
    for (int k=0;k<4;++k){
      int ns = nsc[k], bf = bfc[k];
      size_t hbb = al(8*csz*2);
      size_t uu  = al(16*csz*2);
      size_t bB  = al(csz*(bf?4:2));
      size_t bC  = al(csz*2);
      size_t sg  = al((size_t)cb*ns*17*256*2);
      size_t ov  = (sg > pp_b) ? sg : pp_b;
      if (fixed + hbb + 3*uu + bB + bC + ov <= ws_size){
        CB=cb; NSEG=ns; BCF=bf; hb_b=hbb; u_b=uu; b_b=bB; c_b=bC; sg_b=ov; break;
      }
    }
  }
  if (!CB) return;

  char* ws = (char*)d_ws;
  size_t off = 0;
  auto take = [&](size_t bytes)->char*{ char* p = ws + off; off += bytes; return p; };
  u16*   WT1 = (u16*)take(wt1_b);
  u16*   WT2 = (u16*)take(wt2_b);
  u16*   WT3 = (u16*)take(wt3_b);
  float* PO  = (float*)take(po_b);
  u16*   Hb  = (u16*)take(hb_b);
  u16*   U   = (u16*)take(u_b);
  u16*   ZS  = (u16*)take(u_b);
  u16*   DT  = (u16*)take(u_b);
  void*  Bp  = (void*)take(b_b);
  u16*   Cb  = (u16*)take(c_b);
  u16*   SGH = (u16*)take(sg_b);
  float* PP  = (float*)SGH;                    /* disjoint lifetime */

  prep_kernel<<<3360, 256, 0, stream>>>(in_w, xp_w, dt_w, out_w, WT1, WT2, WT3);

  const int NC = B_SZ / CB;
  const int Mc = CB * SEQ;
  const int L  = SEQ / NSEG;
  const size_t cs = (size_t)Mc*16;
  for (int ci=0; ci<NC; ++ci){
    const int b0 = ci * CB;
    const size_t R0 = (size_t)b0 * SEQ;
    emb_kernel<<<(Mc*DMODEL)/256, 256, 0, stream>>>(x + R0*16, emb_w, emb_b, Hb, cs);
    for (int l=0;l<NLAYERS;++l){
      const float* Al = A_log + (size_t)l*DINNER*DSTATE;
      gemm1_kernel<<<(Mc/256)*2, 256, 0, stream>>>(Hb, WT1 + (size_t)l*512*128,
                                                   in_b + l*512, U, ZS, cs);
      if (BCF){
        gemm2_kernel<1><<<Mc/128, 256, 0, stream>>>(U, WT2 + (size_t)l*288*256,
                                                    xp_b + l*32, dt_b + l*256,
                                                    Bp, Cb, DT, cs);
        scan_p1<1><<<CB*NSEG, 256, 0, stream>>>(U, DT, Bp, Al, SGH, cs, NSEG, L);
        scan_p2<<<CB*16, 256, 0, stream>>>(SGH, Al, NSEG);
        scan_p3<1><<<CB*NSEG, 256, 0, stream>>>(U, DT, Bp, Cb, ZS, Al,
                                                Dp + l*DINNER, SGH, cs, NSEG, L);
      } else {
        gemm2_kernel<0><<<Mc/128, 256, 0, stream>>>(U, WT2 + (size_t)l*288*256,
                                                    xp_b + l*32, dt_b + l*256,
                                                    Bp, Cb, DT, cs);
        scan_p1<0><<<CB*NSEG, 256, 0, stream>>>(U, DT, Bp, Al, SGH, cs, NSEG, L);
        scan_p2<<<CB*16, 256, 0, stream>>>(SGH, Al, NSEG);
        scan_p3<0><<<CB*NSEG, 256, 0, stream>>>(U, DT, Bp, Cb, ZS, Al,
                                                Dp + l*DINNER, SGH, cs, NSEG, L);
      }
      gemm3ln_kernel<<<Mc/128, 256, 0, stream>>>(U, WT3 + (size_t)l*128*256,
                                                 out_b + l*128, ln_g + l*128,
                                                 ln_b + l*128, Hb, cs);
    }
    pool1_kernel<<<CB*16, 128, 0, stream>>>(Hb, PP, cs);
    pool2_kernel<<<CB, 128, 0, stream>>>(PP, PO + (size_t)b0*128);
  }
  head_kernel<<<B_SZ, 64, 0, stream>>>(PO, o1_w, o1_b, o2_w, o2_b, origins, outp);
}